// Round 1
// baseline (444.984 us; speedup 1.0000x reference)
//
#include <hip/hip_runtime.h>
#include <math.h>

#define B_   8
#define S_   512
#define DM_  768
#define H_   12
#define D_   64
#define BH_  96
#define M_   4096   // B_*S_

__device__ __forceinline__ float dual_spike(float x) {
    return x >= 1.0f ? 1.0f : (x <= -1.0f ? -1.0f : 0.0f);
}

// ---------------- Kernel 1: QKV projections ----------------
// out = transform(X @ W + b), written in (B,H,S,D) layout.
// 128x128 tile, BK=16, 256 threads, 8x8 micro-tile (2x2 blocks of 4).
__global__ __launch_bounds__(256) void qkv_gemm(
    const float* __restrict__ X,
    const float* __restrict__ Wq, const float* __restrict__ bq,
    const float* __restrict__ Wk, const float* __restrict__ bk,
    const float* __restrict__ Wv, const float* __restrict__ bv,
    float* __restrict__ q, float* __restrict__ k, float* __restrict__ v)
{
    const int which = blockIdx.z;
    const float* __restrict__ W    = which == 0 ? Wq : (which == 1 ? Wk : Wv);
    const float* __restrict__ bias = which == 0 ? bq : (which == 1 ? bk : bv);
    float* __restrict__ out        = which == 0 ? q  : (which == 1 ? k  : v);

    __shared__ __align__(16) float Xs[16][132];   // [kk][m]
    __shared__ __align__(16) float Ws[16][132];   // [kk][n]

    const int tid = threadIdx.x;
    const int tx = tid & 15, ty = tid >> 4;
    const int m0 = blockIdx.y * 128, n0 = blockIdx.x * 128;

    float acc[8][8];
    #pragma unroll
    for (int i = 0; i < 8; ++i)
        #pragma unroll
        for (int j = 0; j < 8; ++j) acc[i][j] = 0.0f;

    for (int k0 = 0; k0 < DM_; k0 += 16) {
        // stage X tile (128 rows x 16 k), transposed -> Xs[kk][row]
        #pragma unroll
        for (int t = 0; t < 2; ++t) {
            int e = tid + t * 256;             // float4 index 0..511
            int row = e >> 2, c4 = (e & 3) << 2;
            const float4 xv = *reinterpret_cast<const float4*>(&X[(m0 + row) * DM_ + k0 + c4]);
            Xs[c4 + 0][row] = xv.x; Xs[c4 + 1][row] = xv.y;
            Xs[c4 + 2][row] = xv.z; Xs[c4 + 3][row] = xv.w;
        }
        // stage W tile (16 k x 128 n)
        #pragma unroll
        for (int t = 0; t < 2; ++t) {
            int e = tid + t * 256;
            int kk = e >> 5, nn4 = (e & 31) << 2;
            *reinterpret_cast<float4*>(&Ws[kk][nn4]) =
                *reinterpret_cast<const float4*>(&W[(k0 + kk) * DM_ + n0 + nn4]);
        }
        __syncthreads();
        #pragma unroll
        for (int kk = 0; kk < 16; ++kk) {
            float4 a0 = *reinterpret_cast<const float4*>(&Xs[kk][ty * 4]);
            float4 a1 = *reinterpret_cast<const float4*>(&Xs[kk][64 + ty * 4]);
            float4 b0 = *reinterpret_cast<const float4*>(&Ws[kk][tx * 4]);
            float4 b1 = *reinterpret_cast<const float4*>(&Ws[kk][64 + tx * 4]);
            float a[8] = {a0.x,a0.y,a0.z,a0.w,a1.x,a1.y,a1.z,a1.w};
            float b[8] = {b0.x,b0.y,b0.z,b0.w,b1.x,b1.y,b1.z,b1.w};
            #pragma unroll
            for (int i = 0; i < 8; ++i)
                #pragma unroll
                for (int j = 0; j < 8; ++j)
                    acc[i][j] = fmaf(a[i], b[j], acc[i][j]);
        }
        __syncthreads();
    }
    // epilogue: apply bias + transform, write (B,H,S,D)
    #pragma unroll
    for (int ib = 0; ib < 2; ++ib)
    #pragma unroll
    for (int ii = 0; ii < 4; ++ii) {
        int m = m0 + ib * 64 + ty * 4 + ii;
        int b = m >> 9, s = m & 511;
        #pragma unroll
        for (int jb = 0; jb < 2; ++jb) {
            int n_base = n0 + jb * 64 + tx * 4;
            int h = n_base >> 6;
            float vals[4];
            #pragma unroll
            for (int jj = 0; jj < 4; ++jj) {
                float val = acc[ib * 4 + ii][jb * 4 + jj] + bias[n_base + jj];
                if (which == 0)      val = dual_spike(val);
                else if (which == 1) val = 0.5f * dual_spike(val) + 0.5f * val;
                vals[jj] = val;
            }
            float4 o; o.x = vals[0]; o.y = vals[1]; o.z = vals[2]; o.w = vals[3];
            *reinterpret_cast<float4*>(&out[(((b * H_ + h) * S_) + s) * D_ + tx * 4]) = o;
        }
    }
}

// ---------------- Kernel 2: score threshold counts ----------------
// For each (b,h): t[q,k] = (q.k >= 8); accumulate row sums (xh) and col sums (xw).
// Dot accumulation order MUST match attn_pv exactly (bitwise).
__global__ __launch_bounds__(256) void score_sums(
    const float* __restrict__ q, const float* __restrict__ k,
    float* __restrict__ xh, float* __restrict__ xw)
{
    __shared__ __align__(16) float Qt[64][68];   // [d][row]
    __shared__ __align__(16) float Kt[64][68];   // [d][col]
    __shared__ float colred[16][64];

    const int bh = blockIdx.z;
    const int q0 = blockIdx.y * 64, k0 = blockIdx.x * 64;
    const int tid = threadIdx.x, tx = tid & 15, ty = tid >> 4;
    const float* __restrict__ qb = q + bh * S_ * D_;
    const float* __restrict__ kb = k + bh * S_ * D_;

    #pragma unroll
    for (int t = 0; t < 4; ++t) {
        int e = tid + t * 256;
        int r = e >> 4, c4 = (e & 15) << 2;
        const float4 qv = *reinterpret_cast<const float4*>(&qb[(q0 + r) * D_ + c4]);
        Qt[c4+0][r] = qv.x; Qt[c4+1][r] = qv.y; Qt[c4+2][r] = qv.z; Qt[c4+3][r] = qv.w;
        const float4 kv = *reinterpret_cast<const float4*>(&kb[(k0 + r) * D_ + c4]);
        Kt[c4+0][r] = kv.x; Kt[c4+1][r] = kv.y; Kt[c4+2][r] = kv.z; Kt[c4+3][r] = kv.w;
    }
    __syncthreads();

    float dot[4][4];
    #pragma unroll
    for (int i = 0; i < 4; ++i)
        #pragma unroll
        for (int j = 0; j < 4; ++j) dot[i][j] = 0.0f;

    for (int d = 0; d < 64; ++d) {
        float4 av = *reinterpret_cast<const float4*>(&Qt[d][ty * 4]);
        float4 bv = *reinterpret_cast<const float4*>(&Kt[d][tx * 4]);
        float a[4] = {av.x, av.y, av.z, av.w};
        float b[4] = {bv.x, bv.y, bv.z, bv.w};
        #pragma unroll
        for (int i = 0; i < 4; ++i)
            #pragma unroll
            for (int j = 0; j < 4; ++j)
                dot[i][j] = fmaf(a[i], b[j], dot[i][j]);
    }

    float rowc[4] = {0,0,0,0}, colc[4] = {0,0,0,0};
    #pragma unroll
    for (int i = 0; i < 4; ++i)
        #pragma unroll
        for (int j = 0; j < 4; ++j) {
            float t1 = dot[i][j] >= 8.0f ? 1.0f : 0.0f;
            rowc[i] += t1; colc[j] += t1;
        }
    #pragma unroll
    for (int i = 0; i < 4; ++i) {
        float rsum = rowc[i];
        for (int o = 1; o < 16; o <<= 1) rsum += __shfl_xor(rsum, o, 16);
        if (tx == 0) atomicAdd(&xh[bh * S_ + q0 + ty * 4 + i], rsum);
    }
    #pragma unroll
    for (int j = 0; j < 4; ++j) colred[ty][tx * 4 + j] = colc[j];
    __syncthreads();
    if (tid < 64) {
        float ssum = 0.0f;
        #pragma unroll
        for (int t = 0; t < 16; ++t) ssum += colred[t][tid];
        atomicAdd(&xw[bh * S_ + k0 + tid], ssum);
    }
}

// ---------------- Kernel 3: tiny conv / batchnorm / sigmoid ----------------
__global__ __launch_bounds__(1024) void small_ops(
    const float* __restrict__ xh, const float* __restrict__ xw,
    const float* __restrict__ c1w, const float* __restrict__ gamma,
    const float* __restrict__ beta, const float* __restrict__ chw,
    const float* __restrict__ cww,
    float* __restrict__ y, float* __restrict__ s_h, float* __restrict__ s_w)
{
    const int tid = threadIdx.x;
    __shared__ float red[1024];
    __shared__ float c1s[36], chs[36], cws[36];
    __shared__ float mu_s[3], rs_s[3];
    if (tid < 36) { c1s[tid] = c1w[tid]; chs[tid] = chw[tid]; cws[tid] = cww[tid]; }
    __syncthreads();

    // y[b][r][n] = sum_h c1[r,h] * cat[b,h,n],  cat = mean counts / 512
    for (int e = tid; e < B_ * 3 * 1024; e += 1024) {
        int n = e & 1023; int br = e >> 10; int r = br % 3; int b = br / 3;
        float acc = 0.0f;
        #pragma unroll
        for (int h = 0; h < 12; ++h) {
            float cv = (n < 512) ? xh[(b * H_ + h) * S_ + n]
                                 : xw[(b * H_ + h) * S_ + (n - 512)];
            acc = fmaf(c1s[r * 12 + h], cv * (1.0f / 512.0f), acc);
        }
        y[e] = acc;
    }
    __syncthreads();

    // mean per channel r over (b, n): 8192 elems
    for (int r = 0; r < 3; ++r) {
        float s = 0.0f;
        for (int e = tid; e < 8192; e += 1024) {
            int b = e >> 10, n = e & 1023;
            s += y[((b * 3 + r) << 10) | n];
        }
        red[tid] = s; __syncthreads();
        for (int o = 512; o > 0; o >>= 1) { if (tid < o) red[tid] += red[tid + o]; __syncthreads(); }
        if (tid == 0) mu_s[r] = red[0] * (1.0f / 8192.0f);
        __syncthreads();
    }
    // var (two-pass, matches reference arithmetic shape)
    for (int r = 0; r < 3; ++r) {
        float mu = mu_s[r]; float s = 0.0f;
        for (int e = tid; e < 8192; e += 1024) {
            int b = e >> 10, n = e & 1023;
            float d = y[((b * 3 + r) << 10) | n] - mu;
            s = fmaf(d, d, s);
        }
        red[tid] = s; __syncthreads();
        for (int o = 512; o > 0; o >>= 1) { if (tid < o) red[tid] += red[tid + o]; __syncthreads(); }
        if (tid == 0) rs_s[r] = rsqrtf(red[0] * (1.0f / 8192.0f) + 1e-5f);
        __syncthreads();
    }
    // s_h[b,h,s], s_w[b,h,s]
    for (int e = tid; e < B_ * H_ * S_; e += 1024) {
        int s = e & 511; int bh = e >> 9; int h = bh % H_; int b = bh / H_;
        float ah = 0.0f, aw = 0.0f;
        #pragma unroll
        for (int r = 0; r < 3; ++r) {
            int yb = (b * 3 + r) << 10;
            float yh = fmaxf((y[yb + s]       - mu_s[r]) * rs_s[r] * gamma[r] + beta[r], 0.0f);
            float yw = fmaxf((y[yb + 512 + s] - mu_s[r]) * rs_s[r] * gamma[r] + beta[r], 0.0f);
            ah = fmaf(chs[h * 3 + r], yh, ah);
            aw = fmaf(cws[h * 3 + r], yw, aw);
        }
        s_h[e] = 1.0f / (1.0f + expf(-ah));
        s_w[e] = 1.0f / (1.0f + expf(-aw));
    }
}

// ---------------- Kernel 4: recompute scores + bias + online softmax + PV ----------------
__global__ __launch_bounds__(256) void attn_pv(
    const float* __restrict__ q, const float* __restrict__ k,
    const float* __restrict__ v, const float* __restrict__ mask,
    const float* __restrict__ s_h, const float* __restrict__ s_w,
    float* __restrict__ out)
{
    __shared__ __align__(16) float Qt[64][68];   // [d][row]
    __shared__ __align__(16) float Kt[64][68];   // [d][col], reused as P[row][kk]
    __shared__ __align__(16) float Vs[64][68];   // [kk][d]

    const int bh = blockIdx.y;
    const int b = bh / H_, h = bh % H_;
    const int q0 = blockIdx.x * 64;
    const int tid = threadIdx.x, tx = tid & 15, ty = tid >> 4;
    const float* __restrict__ qb = q + bh * S_ * D_;
    const float* __restrict__ kb = k + bh * S_ * D_;
    const float* __restrict__ vb = v + bh * S_ * D_;

    #pragma unroll
    for (int t = 0; t < 4; ++t) {
        int e = tid + t * 256;
        int r = e >> 4, c4 = (e & 15) << 2;
        const float4 qv = *reinterpret_cast<const float4*>(&qb[(q0 + r) * D_ + c4]);
        Qt[c4+0][r] = qv.x; Qt[c4+1][r] = qv.y; Qt[c4+2][r] = qv.z; Qt[c4+3][r] = qv.w;
    }
    float shq[4];
    #pragma unroll
    for (int i = 0; i < 4; ++i) shq[i] = s_h[bh * S_ + q0 + ty * 4 + i];

    float m_r[4], l_r[4], ctx[4][4];
    #pragma unroll
    for (int i = 0; i < 4; ++i) {
        m_r[i] = -INFINITY; l_r[i] = 0.0f;
        #pragma unroll
        for (int j = 0; j < 4; ++j) ctx[i][j] = 0.0f;
    }

    for (int k0 = 0; k0 < S_; k0 += 64) {
        __syncthreads();  // prev PV done (iter0: Q staging done)
        #pragma unroll
        for (int t = 0; t < 4; ++t) {
            int e = tid + t * 256;
            int r = e >> 4, c4 = (e & 15) << 2;
            const float4 kv = *reinterpret_cast<const float4*>(&kb[(k0 + r) * D_ + c4]);
            Kt[c4+0][r] = kv.x; Kt[c4+1][r] = kv.y; Kt[c4+2][r] = kv.z; Kt[c4+3][r] = kv.w;
            *reinterpret_cast<float4*>(&Vs[r][c4]) =
                *reinterpret_cast<const float4*>(&vb[(k0 + r) * D_ + c4]);
        }
        __syncthreads();

        float dot[4][4];
        #pragma unroll
        for (int i = 0; i < 4; ++i)
            #pragma unroll
            for (int j = 0; j < 4; ++j) dot[i][j] = 0.0f;
        for (int d = 0; d < 64; ++d) {
            float4 av = *reinterpret_cast<const float4*>(&Qt[d][ty * 4]);
            float4 bv = *reinterpret_cast<const float4*>(&Kt[d][tx * 4]);
            float a[4] = {av.x, av.y, av.z, av.w};
            float bb[4] = {bv.x, bv.y, bv.z, bv.w};
            #pragma unroll
            for (int i = 0; i < 4; ++i)
                #pragma unroll
                for (int j = 0; j < 4; ++j)
                    dot[i][j] = fmaf(a[i], bb[j], dot[i][j]);
        }

        float swj[4], mj[4];
        #pragma unroll
        for (int j = 0; j < 4; ++j) {
            swj[j] = s_w[bh * S_ + k0 + tx * 4 + j];
            mj[j]  = mask[b * S_ + k0 + tx * 4 + j];
        }
        float sc[4][4];
        #pragma unroll
        for (int i = 0; i < 4; ++i)
            #pragma unroll
            for (int j = 0; j < 4; ++j) {
                float t1 = dot[i][j] >= 8.0f ? 1.0f : 0.0f;
                sc[i][j] = (dot[i][j] * 0.125f + mj[j]) + t1 * (shq[i] * swj[j]);
            }

        float p[4][4], cscale[4];
        #pragma unroll
        for (int i = 0; i < 4; ++i) {
            float tmax = fmaxf(fmaxf(sc[i][0], sc[i][1]), fmaxf(sc[i][2], sc[i][3]));
            for (int o = 1; o < 16; o <<= 1) tmax = fmaxf(tmax, __shfl_xor(tmax, o, 16));
            float mn = fmaxf(m_r[i], tmax);
            float ps = 0.0f;
            #pragma unroll
            for (int j = 0; j < 4; ++j) { p[i][j] = expf(sc[i][j] - mn); ps += p[i][j]; }
            for (int o = 1; o < 16; o <<= 1) ps += __shfl_xor(ps, o, 16);
            float scale = expf(m_r[i] - mn);
            l_r[i] = l_r[i] * scale + ps;
            m_r[i] = mn;
            cscale[i] = scale;
        }
        __syncthreads();  // everyone done reading Kt (dot)
        #pragma unroll
        for (int i = 0; i < 4; ++i)
            #pragma unroll
            for (int j = 0; j < 4; ++j)
                Kt[ty * 4 + i][tx * 4 + j] = p[i][j];
        __syncthreads();
        #pragma unroll
        for (int i = 0; i < 4; ++i)
            #pragma unroll
            for (int j = 0; j < 4; ++j) ctx[i][j] *= cscale[i];
        for (int kk = 0; kk < 64; ++kk) {
            float4 vv = *reinterpret_cast<const float4*>(&Vs[kk][tx * 4]);
            float pv0 = Kt[ty*4+0][kk], pv1 = Kt[ty*4+1][kk];
            float pv2 = Kt[ty*4+2][kk], pv3 = Kt[ty*4+3][kk];
            ctx[0][0] = fmaf(pv0, vv.x, ctx[0][0]); ctx[0][1] = fmaf(pv0, vv.y, ctx[0][1]);
            ctx[0][2] = fmaf(pv0, vv.z, ctx[0][2]); ctx[0][3] = fmaf(pv0, vv.w, ctx[0][3]);
            ctx[1][0] = fmaf(pv1, vv.x, ctx[1][0]); ctx[1][1] = fmaf(pv1, vv.y, ctx[1][1]);
            ctx[1][2] = fmaf(pv1, vv.z, ctx[1][2]); ctx[1][3] = fmaf(pv1, vv.w, ctx[1][3]);
            ctx[2][0] = fmaf(pv2, vv.x, ctx[2][0]); ctx[2][1] = fmaf(pv2, vv.y, ctx[2][1]);
            ctx[2][2] = fmaf(pv2, vv.z, ctx[2][2]); ctx[2][3] = fmaf(pv2, vv.w, ctx[2][3]);
            ctx[3][0] = fmaf(pv3, vv.x, ctx[3][0]); ctx[3][1] = fmaf(pv3, vv.y, ctx[3][1]);
            ctx[3][2] = fmaf(pv3, vv.z, ctx[3][2]); ctx[3][3] = fmaf(pv3, vv.w, ctx[3][3]);
        }
    }
    #pragma unroll
    for (int i = 0; i < 4; ++i) {
        int s = q0 + ty * 4 + i;
        float inv = 1.0f / l_r[i];
        float4 o;
        o.x = ctx[i][0] * inv; o.y = ctx[i][1] * inv;
        o.z = ctx[i][2] * inv; o.w = ctx[i][3] * inv;
        *reinterpret_cast<float4*>(&out[(b * S_ + s) * DM_ + h * D_ + tx * 4]) = o;
    }
}

extern "C" void kernel_launch(void* const* d_in, const int* in_sizes, int n_in,
                              void* d_out, int out_size, void* d_ws, size_t ws_size,
                              hipStream_t stream) {
    const float* X    = (const float*)d_in[0];
    const float* mask = (const float*)d_in[1];
    const float* Wq   = (const float*)d_in[2];
    const float* bq   = (const float*)d_in[3];
    const float* Wk   = (const float*)d_in[4];
    const float* bk   = (const float*)d_in[5];
    const float* Wv   = (const float*)d_in[6];
    const float* bv   = (const float*)d_in[7];
    const float* c1w  = (const float*)d_in[8];
    const float* gam  = (const float*)d_in[9];
    const float* bet  = (const float*)d_in[10];
    const float* chw  = (const float*)d_in[11];
    const float* cww  = (const float*)d_in[12];
    float* out = (float*)d_out;

    float* ws = (float*)d_ws;
    float* q  = ws;                        // 3145728
    float* k  = q  + 3145728;              // 3145728
    float* v  = k  + 3145728;              // 3145728
    float* xh = v  + 3145728;              // 49152
    float* xw = xh + 49152;                // 49152
    float* y  = xw + 49152;                // 24576
    float* sh = y  + 24576;                // 49152
    float* sw = sh + 49152;                // 49152
    // total ~38.6 MB

    hipMemsetAsync(xh, 0, 2 * 49152 * sizeof(float), stream);

    qkv_gemm<<<dim3(6, 32, 3), 256, 0, stream>>>(X, Wq, bq, Wk, bk, Wv, bv, q, k, v);
    score_sums<<<dim3(8, 8, 96), 256, 0, stream>>>(q, k, xh, xw);
    small_ops<<<1, 1024, 0, stream>>>(xh, xw, c1w, gam, bet, chw, cww, y, sh, sw);
    attn_pv<<<dim3(8, 96), 256, 0, stream>>>(q, k, v, mask, sh, sw, out);
}

// Round 2
// 380.625 us; speedup vs baseline: 1.1691x; 1.1691x over previous
//
#include <hip/hip_runtime.h>
#include <math.h>

#define B_   8
#define S_   512
#define DM_  768
#define H_   12
#define D_   64
#define BH_  96
#define M_   4096   // B_*S_

typedef _Float16 f16x8 __attribute__((ext_vector_type(8)));
typedef float    f32x4 __attribute__((ext_vector_type(4)));

__device__ __forceinline__ float dual_spike(float x) {
    return x >= 1.0f ? 1.0f : (x <= -1.0f ? -1.0f : 0.0f);
}

__device__ __forceinline__ void gload_lds16(const void* g, void* l) {
    __builtin_amdgcn_global_load_lds(
        (const __attribute__((address_space(1))) unsigned int*)g,
        (__attribute__((address_space(3))) unsigned int*)l, 16, 0, 0);
}

// ---------------- Prepass: X -> fp16 hi/lo planes, fragment-major tile order ----
// Layout: [mb 32][kc 24][fm 8][g 4][r 16][j 8] halves. One wave per (mb,kc,fm).
__global__ __launch_bounds__(256) void prep_x(
    const float* __restrict__ X, _Float16* __restrict__ Xh, _Float16* __restrict__ Xl)
{
    int wid  = blockIdx.x * 4 + (threadIdx.x >> 6);
    int lane = threadIdx.x & 63;
    int fm = wid & 7, kc = (wid >> 3) % 24, mb = wid / 192;
    int row = mb * 128 + fm * 16 + (lane & 15);
    int col = kc * 32 + (lane >> 4) * 8;
    const float4* p = reinterpret_cast<const float4*>(&X[row * DM_ + col]);
    float4 x0 = p[0], x1 = p[1];
    float xs[8] = {x0.x, x0.y, x0.z, x0.w, x1.x, x1.y, x1.z, x1.w};
    f16x8 hi, lo;
    #pragma unroll
    for (int j = 0; j < 8; ++j) {
        float v = xs[j] * 256.0f;           // exact scale for fp16 denorm headroom
        _Float16 h = (_Float16)v;
        hi[j] = h;
        lo[j] = (_Float16)(v - (float)h);
    }
    size_t out = ((size_t)wid * 64 + lane) * 8;
    *reinterpret_cast<f16x8*>(&Xh[out]) = hi;
    *reinterpret_cast<f16x8*>(&Xl[out]) = lo;
}

// ---------------- Prepass: W (q,k,v) -> transposed fp16 hi/lo planes ------------
// Layout: [which 3][nb 6][kc 24][fn 8][g 4][c 16][j 8] halves. Wave per (which,nb,kc,fn).
__global__ __launch_bounds__(256) void prep_w(
    const float* __restrict__ Wq, const float* __restrict__ Wk, const float* __restrict__ Wv,
    _Float16* __restrict__ Wth, _Float16* __restrict__ Wtl)
{
    int wid  = blockIdx.x * 4 + (threadIdx.x >> 6);
    int lane = threadIdx.x & 63;
    int fn = wid & 7, kc = (wid >> 3) % 24;
    int nb = (wid >> 3) / 24 % 6, which = wid / 1152;
    const float* __restrict__ W = which == 0 ? Wq : (which == 1 ? Wk : Wv);
    int c = lane & 15, g = lane >> 4;
    int ncol = nb * 128 + fn * 16 + c;
    int krow = kc * 32 + g * 8;
    f16x8 hi, lo;
    #pragma unroll
    for (int j = 0; j < 8; ++j) {
        float v = W[(krow + j) * DM_ + ncol] * 256.0f;
        _Float16 h = (_Float16)v;
        hi[j] = h;
        lo[j] = (_Float16)(v - (float)h);
    }
    size_t out = ((size_t)wid * 64 + lane) * 8;
    *reinterpret_cast<f16x8*>(&Wth[out]) = hi;
    *reinterpret_cast<f16x8*>(&Wtl[out]) = lo;
}

// ---------------- Kernel 1: QKV projections via fp16 split MFMA ----------------
// 128x128 tile, 4 waves (2x2), each wave 64x64 (4x4 frags of 16x16x32).
// acc = Ahi*Bhi + Ahi*Blo + Alo*Bhi ; val = acc/65536 + bias.
__global__ __launch_bounds__(256) void qkv_mfma(
    const _Float16* __restrict__ Xh, const _Float16* __restrict__ Xl,
    const _Float16* __restrict__ Wth, const _Float16* __restrict__ Wtl,
    const float* __restrict__ X,
    const float* __restrict__ Wq, const float* __restrict__ bq,
    const float* __restrict__ Wk, const float* __restrict__ bk,
    const float* __restrict__ Wv, const float* __restrict__ bv,
    float* __restrict__ q, float* __restrict__ k, float* __restrict__ v)
{
    const int which = blockIdx.z;
    const int nb = blockIdx.x, mb = blockIdx.y;
    const float* __restrict__ bias = which == 0 ? bq : (which == 1 ? bk : bv);
    float* __restrict__ out        = which == 0 ? q  : (which == 1 ? k  : v);

    __shared__ __align__(16) _Float16 lAh[4096], lAl[4096], lBh[4096], lBl[4096];

    const int tid = threadIdx.x;
    const int wave = tid >> 6, lane = tid & 63;
    const int wm = wave >> 1, wn = wave & 1;
    const int l15 = lane & 15, g = lane >> 4;

    const _Float16* __restrict__ sAh = Xh + (size_t)(mb * 24) * 4096;
    const _Float16* __restrict__ sAl = Xl + (size_t)(mb * 24) * 4096;
    const _Float16* __restrict__ sBh = Wth + (size_t)((which * 6 + nb) * 24) * 4096;
    const _Float16* __restrict__ sBl = Wtl + (size_t)((which * 6 + nb) * 24) * 4096;

    f32x4 acc[4][4];
    #pragma unroll
    for (int i = 0; i < 4; ++i)
        #pragma unroll
        for (int j = 0; j < 4; ++j) acc[i][j] = (f32x4){0.f, 0.f, 0.f, 0.f};

    for (int kc = 0; kc < 24; ++kc) {
        const int co = kc * 4096 + wave * 1024;
        const int lo_ = wave * 1024;
        #pragma unroll
        for (int c = 0; c < 2; ++c) {
            int off = c * 512 + lane * 8;
            int uni = c * 512;          // wave-uniform LDS offset
            gload_lds16(&sAh[co + off], &lAh[lo_ + uni]);
            gload_lds16(&sAl[co + off], &lAl[lo_ + uni]);
            gload_lds16(&sBh[co + off], &lBh[lo_ + uni]);
            gload_lds16(&sBl[co + off], &lBl[lo_ + uni]);
        }
        __syncthreads();   // drains vmcnt -> staged data visible

        f16x8 ah[4], al[4], bh[4], bl[4];
        #pragma unroll
        for (int f = 0; f < 4; ++f) {
            int fa = ((wm * 4 + f) * 4 + g) * 16 + l15;
            ah[f] = *reinterpret_cast<const f16x8*>(&lAh[fa * 8]);
            al[f] = *reinterpret_cast<const f16x8*>(&lAl[fa * 8]);
            int fb = ((wn * 4 + f) * 4 + g) * 16 + l15;
            bh[f] = *reinterpret_cast<const f16x8*>(&lBh[fb * 8]);
            bl[f] = *reinterpret_cast<const f16x8*>(&lBl[fb * 8]);
        }
        #pragma unroll
        for (int i = 0; i < 4; ++i)
            #pragma unroll
            for (int j = 0; j < 4; ++j) {
                acc[i][j] = __builtin_amdgcn_mfma_f32_16x16x32_f16(ah[i], bh[j], acc[i][j], 0, 0, 0);
                acc[i][j] = __builtin_amdgcn_mfma_f32_16x16x32_f16(ah[i], bl[j], acc[i][j], 0, 0, 0);
                acc[i][j] = __builtin_amdgcn_mfma_f32_16x16x32_f16(al[i], bh[j], acc[i][j], 0, 0, 0);
            }
        __syncthreads();   // protect LDS from next-iter staging
    }

    const float* __restrict__ Worig = which == 0 ? Wq : (which == 1 ? Wk : Wv);
    #pragma unroll
    for (int i = 0; i < 4; ++i) {
        #pragma unroll
        for (int j = 0; j < 4; ++j) {
            int n = nb * 128 + wn * 64 + j * 16 + l15;
            int h = n >> 6, d = n & 63;
            float bn = bias[n];
            #pragma unroll
            for (int r = 0; r < 4; ++r) {
                int m = mb * 128 + wm * 64 + i * 16 + g * 4 + r;
                float val = acc[i][j][r] * (1.0f / 65536.0f) + bn;
                if (which < 2) {
                    // near spike-threshold: recompute with the exact sequential
                    // fp32 chain (bit-identical to the validated R1 kernel).
                    if (fabsf(fabsf(val) - 1.0f) < 1e-4f) {
                        float a2 = 0.0f;
                        for (int kk = 0; kk < DM_; ++kk)
                            a2 = fmaf(X[m * DM_ + kk], Worig[kk * DM_ + n], a2);
                        val = a2 + bn;
                    }
                }
                if (which == 0)      val = dual_spike(val);
                else if (which == 1) val = 0.5f * dual_spike(val) + 0.5f * val;
                int b = m >> 9, s = m & 511;
                out[(((b * H_ + h) * S_) + s) * D_ + d] = val;
            }
        }
    }
}

// ---------------- Kernel 2: score threshold counts ----------------
__global__ __launch_bounds__(256) void score_sums(
    const float* __restrict__ q, const float* __restrict__ k,
    float* __restrict__ xh, float* __restrict__ xw)
{
    __shared__ __align__(16) float Qt[64][68];
    __shared__ __align__(16) float Kt[64][68];
    __shared__ float colred[16][64];

    const int bh = blockIdx.z;
    const int q0 = blockIdx.y * 64, k0 = blockIdx.x * 64;
    const int tid = threadIdx.x, tx = tid & 15, ty = tid >> 4;
    const float* __restrict__ qb = q + bh * S_ * D_;
    const float* __restrict__ kb = k + bh * S_ * D_;

    #pragma unroll
    for (int t = 0; t < 4; ++t) {
        int e = tid + t * 256;
        int r = e >> 4, c4 = (e & 15) << 2;
        const float4 qv = *reinterpret_cast<const float4*>(&qb[(q0 + r) * D_ + c4]);
        Qt[c4+0][r] = qv.x; Qt[c4+1][r] = qv.y; Qt[c4+2][r] = qv.z; Qt[c4+3][r] = qv.w;
        const float4 kv = *reinterpret_cast<const float4*>(&kb[(k0 + r) * D_ + c4]);
        Kt[c4+0][r] = kv.x; Kt[c4+1][r] = kv.y; Kt[c4+2][r] = kv.z; Kt[c4+3][r] = kv.w;
    }
    __syncthreads();

    float dot[4][4];
    #pragma unroll
    for (int i = 0; i < 4; ++i)
        #pragma unroll
        for (int j = 0; j < 4; ++j) dot[i][j] = 0.0f;

    for (int d = 0; d < 64; ++d) {
        float4 av = *reinterpret_cast<const float4*>(&Qt[d][ty * 4]);
        float4 bv = *reinterpret_cast<const float4*>(&Kt[d][tx * 4]);
        float a[4] = {av.x, av.y, av.z, av.w};
        float b[4] = {bv.x, bv.y, bv.z, bv.w};
        #pragma unroll
        for (int i = 0; i < 4; ++i)
            #pragma unroll
            for (int j = 0; j < 4; ++j)
                dot[i][j] = fmaf(a[i], b[j], dot[i][j]);
    }

    float rowc[4] = {0,0,0,0}, colc[4] = {0,0,0,0};
    #pragma unroll
    for (int i = 0; i < 4; ++i)
        #pragma unroll
        for (int j = 0; j < 4; ++j) {
            float t1 = dot[i][j] >= 8.0f ? 1.0f : 0.0f;
            rowc[i] += t1; colc[j] += t1;
        }
    #pragma unroll
    for (int i = 0; i < 4; ++i) {
        float rsum = rowc[i];
        for (int o = 1; o < 16; o <<= 1) rsum += __shfl_xor(rsum, o, 16);
        if (tx == 0) atomicAdd(&xh[bh * S_ + q0 + ty * 4 + i], rsum);
    }
    #pragma unroll
    for (int j = 0; j < 4; ++j) colred[ty][tx * 4 + j] = colc[j];
    __syncthreads();
    if (tid < 64) {
        float ssum = 0.0f;
        #pragma unroll
        for (int t = 0; t < 16; ++t) ssum += colred[t][tid];
        atomicAdd(&xw[bh * S_ + k0 + tid], ssum);
    }
}

// ---------------- Kernel 3: tiny conv / batchnorm / sigmoid ----------------
__global__ __launch_bounds__(1024) void small_ops(
    const float* __restrict__ xh, const float* __restrict__ xw,
    const float* __restrict__ c1w, const float* __restrict__ gamma,
    const float* __restrict__ beta, const float* __restrict__ chw,
    const float* __restrict__ cww,
    float* __restrict__ y, float* __restrict__ s_h, float* __restrict__ s_w)
{
    const int tid = threadIdx.x;
    __shared__ float red[1024];
    __shared__ float c1s[36], chs[36], cws[36];
    __shared__ float mu_s[3], rs_s[3];
    if (tid < 36) { c1s[tid] = c1w[tid]; chs[tid] = chw[tid]; cws[tid] = cww[tid]; }
    __syncthreads();

    for (int e = tid; e < B_ * 3 * 1024; e += 1024) {
        int n = e & 1023; int br = e >> 10; int r = br % 3; int b = br / 3;
        float acc = 0.0f;
        #pragma unroll
        for (int h = 0; h < 12; ++h) {
            float cv = (n < 512) ? xh[(b * H_ + h) * S_ + n]
                                 : xw[(b * H_ + h) * S_ + (n - 512)];
            acc = fmaf(c1s[r * 12 + h], cv * (1.0f / 512.0f), acc);
        }
        y[e] = acc;
    }
    __syncthreads();

    for (int r = 0; r < 3; ++r) {
        float s = 0.0f;
        for (int e = tid; e < 8192; e += 1024) {
            int b = e >> 10, n = e & 1023;
            s += y[((b * 3 + r) << 10) | n];
        }
        red[tid] = s; __syncthreads();
        for (int o = 512; o > 0; o >>= 1) { if (tid < o) red[tid] += red[tid + o]; __syncthreads(); }
        if (tid == 0) mu_s[r] = red[0] * (1.0f / 8192.0f);
        __syncthreads();
    }
    for (int r = 0; r < 3; ++r) {
        float mu = mu_s[r]; float s = 0.0f;
        for (int e = tid; e < 8192; e += 1024) {
            int b = e >> 10, n = e & 1023;
            float d = y[((b * 3 + r) << 10) | n] - mu;
            s = fmaf(d, d, s);
        }
        red[tid] = s; __syncthreads();
        for (int o = 512; o > 0; o >>= 1) { if (tid < o) red[tid] += red[tid + o]; __syncthreads(); }
        if (tid == 0) rs_s[r] = rsqrtf(red[0] * (1.0f / 8192.0f) + 1e-5f);
        __syncthreads();
    }
    for (int e = tid; e < B_ * H_ * S_; e += 1024) {
        int s = e & 511; int bh = e >> 9; int h = bh % H_; int b = bh / H_;
        float ah = 0.0f, aw = 0.0f;
        #pragma unroll
        for (int r = 0; r < 3; ++r) {
            int yb = (b * 3 + r) << 10;
            float yh = fmaxf((y[yb + s]       - mu_s[r]) * rs_s[r] * gamma[r] + beta[r], 0.0f);
            float yw = fmaxf((y[yb + 512 + s] - mu_s[r]) * rs_s[r] * gamma[r] + beta[r], 0.0f);
            ah = fmaf(chs[h * 3 + r], yh, ah);
            aw = fmaf(cws[h * 3 + r], yw, aw);
        }
        s_h[e] = 1.0f / (1.0f + expf(-ah));
        s_w[e] = 1.0f / (1.0f + expf(-aw));
    }
}

// ---------------- Kernel 4: recompute scores + bias + online softmax + PV ------
__global__ __launch_bounds__(256) void attn_pv(
    const float* __restrict__ q, const float* __restrict__ k,
    const float* __restrict__ v, const float* __restrict__ mask,
    const float* __restrict__ s_h, const float* __restrict__ s_w,
    float* __restrict__ out)
{
    __shared__ __align__(16) float Qt[64][68];
    __shared__ __align__(16) float Kt[64][68];
    __shared__ __align__(16) float Vs[64][68];

    const int bh = blockIdx.y;
    const int b = bh / H_, h = bh % H_;
    const int q0 = blockIdx.x * 64;
    const int tid = threadIdx.x, tx = tid & 15, ty = tid >> 4;
    const float* __restrict__ qb = q + bh * S_ * D_;
    const float* __restrict__ kb = k + bh * S_ * D_;
    const float* __restrict__ vb = v + bh * S_ * D_;

    #pragma unroll
    for (int t = 0; t < 4; ++t) {
        int e = tid + t * 256;
        int r = e >> 4, c4 = (e & 15) << 2;
        const float4 qv = *reinterpret_cast<const float4*>(&qb[(q0 + r) * D_ + c4]);
        Qt[c4+0][r] = qv.x; Qt[c4+1][r] = qv.y; Qt[c4+2][r] = qv.z; Qt[c4+3][r] = qv.w;
    }
    float shq[4];
    #pragma unroll
    for (int i = 0; i < 4; ++i) shq[i] = s_h[bh * S_ + q0 + ty * 4 + i];

    float m_r[4], l_r[4], ctx[4][4];
    #pragma unroll
    for (int i = 0; i < 4; ++i) {
        m_r[i] = -INFINITY; l_r[i] = 0.0f;
        #pragma unroll
        for (int j = 0; j < 4; ++j) ctx[i][j] = 0.0f;
    }

    for (int k0 = 0; k0 < S_; k0 += 64) {
        __syncthreads();
        #pragma unroll
        for (int t = 0; t < 4; ++t) {
            int e = tid + t * 256;
            int r = e >> 4, c4 = (e & 15) << 2;
            const float4 kv = *reinterpret_cast<const float4*>(&kb[(k0 + r) * D_ + c4]);
            Kt[c4+0][r] = kv.x; Kt[c4+1][r] = kv.y; Kt[c4+2][r] = kv.z; Kt[c4+3][r] = kv.w;
            *reinterpret_cast<float4*>(&Vs[r][c4]) =
                *reinterpret_cast<const float4*>(&vb[(k0 + r) * D_ + c4]);
        }
        __syncthreads();

        float dot[4][4];
        #pragma unroll
        for (int i = 0; i < 4; ++i)
            #pragma unroll
            for (int j = 0; j < 4; ++j) dot[i][j] = 0.0f;
        for (int d = 0; d < 64; ++d) {
            float4 av = *reinterpret_cast<const float4*>(&Qt[d][ty * 4]);
            float4 bv = *reinterpret_cast<const float4*>(&Kt[d][tx * 4]);
            float a[4] = {av.x, av.y, av.z, av.w};
            float bb[4] = {bv.x, bv.y, bv.z, bv.w};
            #pragma unroll
            for (int i = 0; i < 4; ++i)
                #pragma unroll
                for (int j = 0; j < 4; ++j)
                    dot[i][j] = fmaf(a[i], bb[j], dot[i][j]);
        }

        float swj[4], mj[4];
        #pragma unroll
        for (int j = 0; j < 4; ++j) {
            swj[j] = s_w[bh * S_ + k0 + tx * 4 + j];
            mj[j]  = mask[b * S_ + k0 + tx * 4 + j];
        }
        float sc[4][4];
        #pragma unroll
        for (int i = 0; i < 4; ++i)
            #pragma unroll
            for (int j = 0; j < 4; ++j) {
                float t1 = dot[i][j] >= 8.0f ? 1.0f : 0.0f;
                sc[i][j] = (dot[i][j] * 0.125f + mj[j]) + t1 * (shq[i] * swj[j]);
            }

        float p[4][4], cscale[4];
        #pragma unroll
        for (int i = 0; i < 4; ++i) {
            float tmax = fmaxf(fmaxf(sc[i][0], sc[i][1]), fmaxf(sc[i][2], sc[i][3]));
            for (int o = 1; o < 16; o <<= 1) tmax = fmaxf(tmax, __shfl_xor(tmax, o, 16));
            float mn = fmaxf(m_r[i], tmax);
            float ps = 0.0f;
            #pragma unroll
            for (int j = 0; j < 4; ++j) { p[i][j] = expf(sc[i][j] - mn); ps += p[i][j]; }
            for (int o = 1; o < 16; o <<= 1) ps += __shfl_xor(ps, o, 16);
            float scale = expf(m_r[i] - mn);
            l_r[i] = l_r[i] * scale + ps;
            m_r[i] = mn;
            cscale[i] = scale;
        }
        __syncthreads();
        #pragma unroll
        for (int i = 0; i < 4; ++i)
            #pragma unroll
            for (int j = 0; j < 4; ++j)
                Kt[ty * 4 + i][tx * 4 + j] = p[i][j];
        __syncthreads();
        #pragma unroll
        for (int i = 0; i < 4; ++i)
            #pragma unroll
            for (int j = 0; j < 4; ++j) ctx[i][j] *= cscale[i];
        for (int kk = 0; kk < 64; ++kk) {
            float4 vv = *reinterpret_cast<const float4*>(&Vs[kk][tx * 4]);
            float pv0 = Kt[ty*4+0][kk], pv1 = Kt[ty*4+1][kk];
            float pv2 = Kt[ty*4+2][kk], pv3 = Kt[ty*4+3][kk];
            ctx[0][0] = fmaf(pv0, vv.x, ctx[0][0]); ctx[0][1] = fmaf(pv0, vv.y, ctx[0][1]);
            ctx[0][2] = fmaf(pv0, vv.z, ctx[0][2]); ctx[0][3] = fmaf(pv0, vv.w, ctx[0][3]);
            ctx[1][0] = fmaf(pv1, vv.x, ctx[1][0]); ctx[1][1] = fmaf(pv1, vv.y, ctx[1][1]);
            ctx[1][2] = fmaf(pv1, vv.z, ctx[1][2]); ctx[1][3] = fmaf(pv1, vv.w, ctx[1][3]);
            ctx[2][0] = fmaf(pv2, vv.x, ctx[2][0]); ctx[2][1] = fmaf(pv2, vv.y, ctx[2][1]);
            ctx[2][2] = fmaf(pv2, vv.z, ctx[2][2]); ctx[2][3] = fmaf(pv2, vv.w, ctx[2][3]);
            ctx[3][0] = fmaf(pv3, vv.x, ctx[3][0]); ctx[3][1] = fmaf(pv3, vv.y, ctx[3][1]);
            ctx[3][2] = fmaf(pv3, vv.z, ctx[3][2]); ctx[3][3] = fmaf(pv3, vv.w, ctx[3][3]);
        }
    }
    #pragma unroll
    for (int i = 0; i < 4; ++i) {
        int s = q0 + ty * 4 + i;
        float inv = 1.0f / l_r[i];
        float4 o;
        o.x = ctx[i][0] * inv; o.y = ctx[i][1] * inv;
        o.z = ctx[i][2] * inv; o.w = ctx[i][3] * inv;
        *reinterpret_cast<float4*>(&out[(b * S_ + s) * DM_ + h * D_ + tx * 4]) = o;
    }
}

extern "C" void kernel_launch(void* const* d_in, const int* in_sizes, int n_in,
                              void* d_out, int out_size, void* d_ws, size_t ws_size,
                              hipStream_t stream) {
    const float* X    = (const float*)d_in[0];
    const float* mask = (const float*)d_in[1];
    const float* Wq   = (const float*)d_in[2];
    const float* bq   = (const float*)d_in[3];
    const float* Wk   = (const float*)d_in[4];
    const float* bk   = (const float*)d_in[5];
    const float* Wv   = (const float*)d_in[6];
    const float* bv   = (const float*)d_in[7];
    const float* c1w  = (const float*)d_in[8];
    const float* gam  = (const float*)d_in[9];
    const float* bet  = (const float*)d_in[10];
    const float* chw  = (const float*)d_in[11];
    const float* cww  = (const float*)d_in[12];
    float* out = (float*)d_out;

    float* ws = (float*)d_ws;
    float* q  = ws;                        // 3145728 f32
    float* k  = q  + 3145728;
    float* v  = k  + 3145728;
    float* xh = v  + 3145728;              // 49152
    float* xw = xh + 49152;
    float* y  = xw + 49152;                // 24576
    float* sh = y  + 24576;
    float* sw = sh + 49152;
    _Float16* Xh  = (_Float16*)(sw + 49152);   // 3145728 halves
    _Float16* Xl  = Xh + 3145728;
    _Float16* Wth = Xl + 3145728;              // 1769472 halves
    _Float16* Wtl = Wth + 1769472;             // total ws ~55.6 MiB

    hipMemsetAsync(xh, 0, 2 * 49152 * sizeof(float), stream);

    prep_x<<<1536, 256, 0, stream>>>(X, Xh, Xl);
    prep_w<<<864, 256, 0, stream>>>(Wq, Wk, Wv, Wth, Wtl);
    qkv_mfma<<<dim3(6, 32, 3), 256, 0, stream>>>(Xh, Xl, Wth, Wtl,
        X, Wq, bq, Wk, bk, Wv, bv, q, k, v);
    score_sums<<<dim3(8, 8, 96), 256, 0, stream>>>(q, k, xh, xw);
    small_ops<<<1, 1024, 0, stream>>>(xh, xw, c1w, gam, bet, chw, cww, y, sh, sw);
    attn_pv<<<dim3(8, 96), 256, 0, stream>>>(q, k, v, mask, sh, sw, out);
}

// Round 3
// 378.880 us; speedup vs baseline: 1.1745x; 1.0046x over previous
//
#include <hip/hip_runtime.h>
#include <math.h>

#define B_   8
#define S_   512
#define DM_  768
#define H_   12
#define D_   64
#define BH_  96
#define M_   4096   // B_*S_

typedef _Float16 f16x8 __attribute__((ext_vector_type(8)));
typedef float    f32x4 __attribute__((ext_vector_type(4)));

__device__ __forceinline__ float dual_spike(float x) {
    return x >= 1.0f ? 1.0f : (x <= -1.0f ? -1.0f : 0.0f);
}

__device__ __forceinline__ void gload_lds16(const void* g, void* l) {
    __builtin_amdgcn_global_load_lds(
        (const __attribute__((address_space(1))) unsigned int*)g,
        (__attribute__((address_space(3))) unsigned int*)l, 16, 0, 0);
}

// ---------------- Prepass: X -> fp16 hi/lo planes, fragment-major tile order ----
// Layout: [mb 32][kc 24][fm 8][g 4][r 16][j 8] halves. One wave per (mb,kc,fm).
__global__ __launch_bounds__(256) void prep_x(
    const float* __restrict__ X, _Float16* __restrict__ Xh, _Float16* __restrict__ Xl)
{
    int wid  = blockIdx.x * 4 + (threadIdx.x >> 6);
    int lane = threadIdx.x & 63;
    int fm = wid & 7, kc = (wid >> 3) % 24, mb = wid / 192;
    int row = mb * 128 + fm * 16 + (lane & 15);
    int col = kc * 32 + (lane >> 4) * 8;
    const float4* p = reinterpret_cast<const float4*>(&X[row * DM_ + col]);
    float4 x0 = p[0], x1 = p[1];
    float xs[8] = {x0.x, x0.y, x0.z, x0.w, x1.x, x1.y, x1.z, x1.w};
    f16x8 hi, lo;
    #pragma unroll
    for (int j = 0; j < 8; ++j) {
        float v = xs[j] * 256.0f;           // exact scale for fp16 denorm headroom
        _Float16 h = (_Float16)v;
        hi[j] = h;
        lo[j] = (_Float16)(v - (float)h);
    }
    size_t out = ((size_t)wid * 64 + lane) * 8;
    *reinterpret_cast<f16x8*>(&Xh[out]) = hi;
    *reinterpret_cast<f16x8*>(&Xl[out]) = lo;
}

// ---------------- Prepass: W (q,k,v) -> transposed fp16 hi/lo planes ------------
// Layout: [which 3][nb 6][kc 24][fn 8][g 4][c 16][j 8] halves. Wave per (which,nb,kc,fn).
__global__ __launch_bounds__(256) void prep_w(
    const float* __restrict__ Wq, const float* __restrict__ Wk, const float* __restrict__ Wv,
    _Float16* __restrict__ Wth, _Float16* __restrict__ Wtl)
{
    int wid  = blockIdx.x * 4 + (threadIdx.x >> 6);
    int lane = threadIdx.x & 63;
    int fn = wid & 7, kc = (wid >> 3) % 24;
    int nb = (wid >> 3) / 24 % 6, which = wid / 1152;
    const float* __restrict__ W = which == 0 ? Wq : (which == 1 ? Wk : Wv);
    int c = lane & 15, g = lane >> 4;
    int ncol = nb * 128 + fn * 16 + c;
    int krow = kc * 32 + g * 8;
    f16x8 hi, lo;
    #pragma unroll
    for (int j = 0; j < 8; ++j) {
        float v = W[(krow + j) * DM_ + ncol] * 256.0f;
        _Float16 h = (_Float16)v;
        hi[j] = h;
        lo[j] = (_Float16)(v - (float)h);
    }
    size_t out = ((size_t)wid * 64 + lane) * 8;
    *reinterpret_cast<f16x8*>(&Wth[out]) = hi;
    *reinterpret_cast<f16x8*>(&Wtl[out]) = lo;
}

// ---------------- Kernel 1: QKV projections via fp16 split MFMA ----------------
// 128x128 tile, 4 waves (2x2), each wave 64x64 (4x4 frags of 16x16x32).
// acc = Ahi*Bhi + Ahi*Blo + Alo*Bhi ; val = acc/65536 + bias.
// v3: double-buffered LDS + prefetch-before-compute (one barrier/iter) + XCD swizzle.
__global__ __launch_bounds__(256, 2) void qkv_mfma(
    const _Float16* __restrict__ Xh, const _Float16* __restrict__ Xl,
    const _Float16* __restrict__ Wth, const _Float16* __restrict__ Wtl,
    const float* __restrict__ X,
    const float* __restrict__ Wq, const float* __restrict__ bq,
    const float* __restrict__ Wk, const float* __restrict__ bk,
    const float* __restrict__ Wv, const float* __restrict__ bv,
    float* __restrict__ q, float* __restrict__ k, float* __restrict__ v)
{
    // XCD-bijective swizzle: nwg = 576 = 8 * 72. Consecutive HW dispatch ids
    // round-robin XCDs; give each XCD a contiguous which-major chunk
    // (one W plane pair + 12 X row-panels -> ~7 MB working set per XCD L2).
    const int orig = blockIdx.x;
    const int wg = (orig & 7) * 72 + (orig >> 3);
    const int which = wg / 192;
    const int rem = wg % 192;
    const int mb = rem / 6, nb = rem % 6;

    const float* __restrict__ bias = which == 0 ? bq : (which == 1 ? bk : bv);
    float* __restrict__ out        = which == 0 ? q  : (which == 1 ? k  : v);

    // [buf][plane Ah,Al,Bh,Bl][4096 halves]
    __shared__ __align__(16) _Float16 lds[2][4][4096];

    const int tid = threadIdx.x;
    const int wave = tid >> 6, lane = tid & 63;
    const int wm = wave >> 1, wn = wave & 1;
    const int l15 = lane & 15, g = lane >> 4;

    const _Float16* __restrict__ sAh = Xh + (size_t)(mb * 24) * 4096;
    const _Float16* __restrict__ sAl = Xl + (size_t)(mb * 24) * 4096;
    const _Float16* __restrict__ sBh = Wth + (size_t)((which * 6 + nb) * 24) * 4096;
    const _Float16* __restrict__ sBl = Wtl + (size_t)((which * 6 + nb) * 24) * 4096;

    f32x4 acc[4][4];
    #pragma unroll
    for (int i = 0; i < 4; ++i)
        #pragma unroll
        for (int j = 0; j < 4; ++j) acc[i][j] = (f32x4){0.f, 0.f, 0.f, 0.f};

    // per-wave staging of one kc tile into buffer bsel
    auto stage = [&](int kc, int bsel) {
        const int so = kc * 4096 + wave * 1024;
        const int uni = wave * 1024;
        #pragma unroll
        for (int c = 0; c < 2; ++c) {
            int off = so + c * 512 + lane * 8;
            int u = uni + c * 512;
            gload_lds16(&sAh[off], &lds[bsel][0][u]);
            gload_lds16(&sAl[off], &lds[bsel][1][u]);
            gload_lds16(&sBh[off], &lds[bsel][2][u]);
            gload_lds16(&sBl[off], &lds[bsel][3][u]);
        }
    };

    stage(0, 0);
    __syncthreads();           // prologue: buf0 ready
    int cur = 0;

    for (int kc = 0; kc < 24; ++kc) {
        if (kc + 1 < 24) stage(kc + 1, cur ^ 1);   // prefetch next tile (in flight during MFMA)

        f16x8 ah[4], al[4], bh[4], bl[4];
        #pragma unroll
        for (int f = 0; f < 4; ++f) {
            int fa = ((wm * 4 + f) * 4 + g) * 16 + l15;
            ah[f] = *reinterpret_cast<const f16x8*>(&lds[cur][0][fa * 8]);
            al[f] = *reinterpret_cast<const f16x8*>(&lds[cur][1][fa * 8]);
            int fb = ((wn * 4 + f) * 4 + g) * 16 + l15;
            bh[f] = *reinterpret_cast<const f16x8*>(&lds[cur][2][fb * 8]);
            bl[f] = *reinterpret_cast<const f16x8*>(&lds[cur][3][fb * 8]);
        }
        #pragma unroll
        for (int i = 0; i < 4; ++i)
            #pragma unroll
            for (int j = 0; j < 4; ++j) {
                acc[i][j] = __builtin_amdgcn_mfma_f32_16x16x32_f16(ah[i], bh[j], acc[i][j], 0, 0, 0);
                acc[i][j] = __builtin_amdgcn_mfma_f32_16x16x32_f16(ah[i], bl[j], acc[i][j], 0, 0, 0);
                acc[i][j] = __builtin_amdgcn_mfma_f32_16x16x32_f16(al[i], bh[j], acc[i][j], 0, 0, 0);
            }
        __syncthreads();       // drains prefetch vmcnt + our lgkm; buffers swap safely
        cur ^= 1;
    }

    const float* __restrict__ Worig = which == 0 ? Wq : (which == 1 ? Wk : Wv);
    #pragma unroll
    for (int i = 0; i < 4; ++i) {
        #pragma unroll
        for (int j = 0; j < 4; ++j) {
            int n = nb * 128 + wn * 64 + j * 16 + l15;
            int h = n >> 6, d = n & 63;
            float bn = bias[n];
            #pragma unroll
            for (int r = 0; r < 4; ++r) {
                int m = mb * 128 + wm * 64 + i * 16 + g * 4 + r;
                float val = acc[i][j][r] * (1.0f / 65536.0f) + bn;
                if (which < 2) {
                    // near spike-threshold: recompute with the exact sequential
                    // fp32 chain (bit-identical to the validated R1 kernel).
                    if (fabsf(fabsf(val) - 1.0f) < 1e-4f) {
                        float a2 = 0.0f;
                        for (int kk = 0; kk < DM_; ++kk)
                            a2 = fmaf(X[m * DM_ + kk], Worig[kk * DM_ + n], a2);
                        val = a2 + bn;
                    }
                }
                if (which == 0)      val = dual_spike(val);
                else if (which == 1) val = 0.5f * dual_spike(val) + 0.5f * val;
                int b = m >> 9, s = m & 511;
                out[(((b * H_ + h) * S_) + s) * D_ + d] = val;
            }
        }
    }
}

// ---------------- Kernel 2: score threshold counts ----------------
__global__ __launch_bounds__(256) void score_sums(
    const float* __restrict__ q, const float* __restrict__ k,
    float* __restrict__ xh, float* __restrict__ xw)
{
    __shared__ __align__(16) float Qt[64][68];
    __shared__ __align__(16) float Kt[64][68];
    __shared__ float colred[16][64];

    const int bh = blockIdx.z;
    const int q0 = blockIdx.y * 64, k0 = blockIdx.x * 64;
    const int tid = threadIdx.x, tx = tid & 15, ty = tid >> 4;
    const float* __restrict__ qb = q + bh * S_ * D_;
    const float* __restrict__ kb = k + bh * S_ * D_;

    #pragma unroll
    for (int t = 0; t < 4; ++t) {
        int e = tid + t * 256;
        int r = e >> 4, c4 = (e & 15) << 2;
        const float4 qv = *reinterpret_cast<const float4*>(&qb[(q0 + r) * D_ + c4]);
        Qt[c4+0][r] = qv.x; Qt[c4+1][r] = qv.y; Qt[c4+2][r] = qv.z; Qt[c4+3][r] = qv.w;
        const float4 kv = *reinterpret_cast<const float4*>(&kb[(k0 + r) * D_ + c4]);
        Kt[c4+0][r] = kv.x; Kt[c4+1][r] = kv.y; Kt[c4+2][r] = kv.z; Kt[c4+3][r] = kv.w;
    }
    __syncthreads();

    float dot[4][4];
    #pragma unroll
    for (int i = 0; i < 4; ++i)
        #pragma unroll
        for (int j = 0; j < 4; ++j) dot[i][j] = 0.0f;

    for (int d = 0; d < 64; ++d) {
        float4 av = *reinterpret_cast<const float4*>(&Qt[d][ty * 4]);
        float4 bv = *reinterpret_cast<const float4*>(&Kt[d][tx * 4]);
        float a[4] = {av.x, av.y, av.z, av.w};
        float b[4] = {bv.x, bv.y, bv.z, bv.w};
        #pragma unroll
        for (int i = 0; i < 4; ++i)
            #pragma unroll
            for (int j = 0; j < 4; ++j)
                dot[i][j] = fmaf(a[i], b[j], dot[i][j]);
    }

    float rowc[4] = {0,0,0,0}, colc[4] = {0,0,0,0};
    #pragma unroll
    for (int i = 0; i < 4; ++i)
        #pragma unroll
        for (int j = 0; j < 4; ++j) {
            float t1 = dot[i][j] >= 8.0f ? 1.0f : 0.0f;
            rowc[i] += t1; colc[j] += t1;
        }
    #pragma unroll
    for (int i = 0; i < 4; ++i) {
        float rsum = rowc[i];
        for (int o = 1; o < 16; o <<= 1) rsum += __shfl_xor(rsum, o, 16);
        if (tx == 0) atomicAdd(&xh[bh * S_ + q0 + ty * 4 + i], rsum);
    }
    #pragma unroll
    for (int j = 0; j < 4; ++j) colred[ty][tx * 4 + j] = colc[j];
    __syncthreads();
    if (tid < 64) {
        float ssum = 0.0f;
        #pragma unroll
        for (int t = 0; t < 16; ++t) ssum += colred[t][tid];
        atomicAdd(&xw[bh * S_ + k0 + tid], ssum);
    }
}

// ---------------- Kernel 3: tiny conv / batchnorm / sigmoid ----------------
__global__ __launch_bounds__(1024) void small_ops(
    const float* __restrict__ xh, const float* __restrict__ xw,
    const float* __restrict__ c1w, const float* __restrict__ gamma,
    const float* __restrict__ beta, const float* __restrict__ chw,
    const float* __restrict__ cww,
    float* __restrict__ y, float* __restrict__ s_h, float* __restrict__ s_w)
{
    const int tid = threadIdx.x;
    __shared__ float red[1024];
    __shared__ float c1s[36], chs[36], cws[36];
    __shared__ float mu_s[3], rs_s[3];
    if (tid < 36) { c1s[tid] = c1w[tid]; chs[tid] = chw[tid]; cws[tid] = cww[tid]; }
    __syncthreads();

    for (int e = tid; e < B_ * 3 * 1024; e += 1024) {
        int n = e & 1023; int br = e >> 10; int r = br % 3; int b = br / 3;
        float acc = 0.0f;
        #pragma unroll
        for (int h = 0; h < 12; ++h) {
            float cv = (n < 512) ? xh[(b * H_ + h) * S_ + n]
                                 : xw[(b * H_ + h) * S_ + (n - 512)];
            acc = fmaf(c1s[r * 12 + h], cv * (1.0f / 512.0f), acc);
        }
        y[e] = acc;
    }
    __syncthreads();

    for (int r = 0; r < 3; ++r) {
        float s = 0.0f;
        for (int e = tid; e < 8192; e += 1024) {
            int b = e >> 10, n = e & 1023;
            s += y[((b * 3 + r) << 10) | n];
        }
        red[tid] = s; __syncthreads();
        for (int o = 512; o > 0; o >>= 1) { if (tid < o) red[tid] += red[tid + o]; __syncthreads(); }
        if (tid == 0) mu_s[r] = red[0] * (1.0f / 8192.0f);
        __syncthreads();
    }
    for (int r = 0; r < 3; ++r) {
        float mu = mu_s[r]; float s = 0.0f;
        for (int e = tid; e < 8192; e += 1024) {
            int b = e >> 10, n = e & 1023;
            float d = y[((b * 3 + r) << 10) | n] - mu;
            s = fmaf(d, d, s);
        }
        red[tid] = s; __syncthreads();
        for (int o = 512; o > 0; o >>= 1) { if (tid < o) red[tid] += red[tid + o]; __syncthreads(); }
        if (tid == 0) rs_s[r] = rsqrtf(red[0] * (1.0f / 8192.0f) + 1e-5f);
        __syncthreads();
    }
    for (int e = tid; e < B_ * H_ * S_; e += 1024) {
        int s = e & 511; int bh = e >> 9; int h = bh % H_; int b = bh / H_;
        float ah = 0.0f, aw = 0.0f;
        #pragma unroll
        for (int r = 0; r < 3; ++r) {
            int yb = (b * 3 + r) << 10;
            float yh = fmaxf((y[yb + s]       - mu_s[r]) * rs_s[r] * gamma[r] + beta[r], 0.0f);
            float yw = fmaxf((y[yb + 512 + s] - mu_s[r]) * rs_s[r] * gamma[r] + beta[r], 0.0f);
            ah = fmaf(chs[h * 3 + r], yh, ah);
            aw = fmaf(cws[h * 3 + r], yw, aw);
        }
        s_h[e] = 1.0f / (1.0f + expf(-ah));
        s_w[e] = 1.0f / (1.0f + expf(-aw));
    }
}

// ---------------- Kernel 4: recompute scores + bias + online softmax + PV ------
__global__ __launch_bounds__(256) void attn_pv(
    const float* __restrict__ q, const float* __restrict__ k,
    const float* __restrict__ v, const float* __restrict__ mask,
    const float* __restrict__ s_h, const float* __restrict__ s_w,
    float* __restrict__ out)
{
    __shared__ __align__(16) float Qt[64][68];
    __shared__ __align__(16) float Kt[64][68];
    __shared__ __align__(16) float Vs[64][68];

    const int bh = blockIdx.y;
    const int b = bh / H_, h = bh % H_;
    const int q0 = blockIdx.x * 64;
    const int tid = threadIdx.x, tx = tid & 15, ty = tid >> 4;
    const float* __restrict__ qb = q + bh * S_ * D_;
    const float* __restrict__ kb = k + bh * S_ * D_;
    const float* __restrict__ vb = v + bh * S_ * D_;

    #pragma unroll
    for (int t = 0; t < 4; ++t) {
        int e = tid + t * 256;
        int r = e >> 4, c4 = (e & 15) << 2;
        const float4 qv = *reinterpret_cast<const float4*>(&qb[(q0 + r) * D_ + c4]);
        Qt[c4+0][r] = qv.x; Qt[c4+1][r] = qv.y; Qt[c4+2][r] = qv.z; Qt[c4+3][r] = qv.w;
    }
    float shq[4];
    #pragma unroll
    for (int i = 0; i < 4; ++i) shq[i] = s_h[bh * S_ + q0 + ty * 4 + i];

    float m_r[4], l_r[4], ctx[4][4];
    #pragma unroll
    for (int i = 0; i < 4; ++i) {
        m_r[i] = -INFINITY; l_r[i] = 0.0f;
        #pragma unroll
        for (int j = 0; j < 4; ++j) ctx[i][j] = 0.0f;
    }

    for (int k0 = 0; k0 < S_; k0 += 64) {
        __syncthreads();
        #pragma unroll
        for (int t = 0; t < 4; ++t) {
            int e = tid + t * 256;
            int r = e >> 4, c4 = (e & 15) << 2;
            const float4 kv = *reinterpret_cast<const float4*>(&kb[(k0 + r) * D_ + c4]);
            Kt[c4+0][r] = kv.x; Kt[c4+1][r] = kv.y; Kt[c4+2][r] = kv.z; Kt[c4+3][r] = kv.w;
            *reinterpret_cast<float4*>(&Vs[r][c4]) =
                *reinterpret_cast<const float4*>(&vb[(k0 + r) * D_ + c4]);
        }
        __syncthreads();

        float dot[4][4];
        #pragma unroll
        for (int i = 0; i < 4; ++i)
            #pragma unroll
            for (int j = 0; j < 4; ++j) dot[i][j] = 0.0f;
        for (int d = 0; d < 64; ++d) {
            float4 av = *reinterpret_cast<const float4*>(&Qt[d][ty * 4]);
            float4 bv = *reinterpret_cast<const float4*>(&Kt[d][tx * 4]);
            float a[4] = {av.x, av.y, av.z, av.w};
            float bb[4] = {bv.x, bv.y, bv.z, bv.w};
            #pragma unroll
            for (int i = 0; i < 4; ++i)
                #pragma unroll
                for (int j = 0; j < 4; ++j)
                    dot[i][j] = fmaf(a[i], bb[j], dot[i][j]);
        }

        float swj[4], mj[4];
        #pragma unroll
        for (int j = 0; j < 4; ++j) {
            swj[j] = s_w[bh * S_ + k0 + tx * 4 + j];
            mj[j]  = mask[b * S_ + k0 + tx * 4 + j];
        }
        float sc[4][4];
        #pragma unroll
        for (int i = 0; i < 4; ++i)
            #pragma unroll
            for (int j = 0; j < 4; ++j) {
                float t1 = dot[i][j] >= 8.0f ? 1.0f : 0.0f;
                sc[i][j] = (dot[i][j] * 0.125f + mj[j]) + t1 * (shq[i] * swj[j]);
            }

        float p[4][4], cscale[4];
        #pragma unroll
        for (int i = 0; i < 4; ++i) {
            float tmax = fmaxf(fmaxf(sc[i][0], sc[i][1]), fmaxf(sc[i][2], sc[i][3]));
            for (int o = 1; o < 16; o <<= 1) tmax = fmaxf(tmax, __shfl_xor(tmax, o, 16));
            float mn = fmaxf(m_r[i], tmax);
            float ps = 0.0f;
            #pragma unroll
            for (int j = 0; j < 4; ++j) { p[i][j] = expf(sc[i][j] - mn); ps += p[i][j]; }
            for (int o = 1; o < 16; o <<= 1) ps += __shfl_xor(ps, o, 16);
            float scale = expf(m_r[i] - mn);
            l_r[i] = l_r[i] * scale + ps;
            m_r[i] = mn;
            cscale[i] = scale;
        }
        __syncthreads();
        #pragma unroll
        for (int i = 0; i < 4; ++i)
            #pragma unroll
            for (int j = 0; j < 4; ++j)
                Kt[ty * 4 + i][tx * 4 + j] = p[i][j];
        __syncthreads();
        #pragma unroll
        for (int i = 0; i < 4; ++i)
            #pragma unroll
            for (int j = 0; j < 4; ++j) ctx[i][j] *= cscale[i];
        for (int kk = 0; kk < 64; ++kk) {
            float4 vv = *reinterpret_cast<const float4*>(&Vs[kk][tx * 4]);
            float pv0 = Kt[ty*4+0][kk], pv1 = Kt[ty*4+1][kk];
            float pv2 = Kt[ty*4+2][kk], pv3 = Kt[ty*4+3][kk];
            ctx[0][0] = fmaf(pv0, vv.x, ctx[0][0]); ctx[0][1] = fmaf(pv0, vv.y, ctx[0][1]);
            ctx[0][2] = fmaf(pv0, vv.z, ctx[0][2]); ctx[0][3] = fmaf(pv0, vv.w, ctx[0][3]);
            ctx[1][0] = fmaf(pv1, vv.x, ctx[1][0]); ctx[1][1] = fmaf(pv1, vv.y, ctx[1][1]);
            ctx[1][2] = fmaf(pv1, vv.z, ctx[1][2]); ctx[1][3] = fmaf(pv1, vv.w, ctx[1][3]);
            ctx[2][0] = fmaf(pv2, vv.x, ctx[2][0]); ctx[2][1] = fmaf(pv2, vv.y, ctx[2][1]);
            ctx[2][2] = fmaf(pv2, vv.z, ctx[2][2]); ctx[2][3] = fmaf(pv2, vv.w, ctx[2][3]);
            ctx[3][0] = fmaf(pv3, vv.x, ctx[3][0]); ctx[3][1] = fmaf(pv3, vv.y, ctx[3][1]);
            ctx[3][2] = fmaf(pv3, vv.z, ctx[3][2]); ctx[3][3] = fmaf(pv3, vv.w, ctx[3][3]);
        }
    }
    #pragma unroll
    for (int i = 0; i < 4; ++i) {
        int s = q0 + ty * 4 + i;
        float inv = 1.0f / l_r[i];
        float4 o;
        o.x = ctx[i][0] * inv; o.y = ctx[i][1] * inv;
        o.z = ctx[i][2] * inv; o.w = ctx[i][3] * inv;
        *reinterpret_cast<float4*>(&out[(b * S_ + s) * DM_ + h * D_ + tx * 4]) = o;
    }
}

extern "C" void kernel_launch(void* const* d_in, const int* in_sizes, int n_in,
                              void* d_out, int out_size, void* d_ws, size_t ws_size,
                              hipStream_t stream) {
    const float* X    = (const float*)d_in[0];
    const float* mask = (const float*)d_in[1];
    const float* Wq   = (const float*)d_in[2];
    const float* bq   = (const float*)d_in[3];
    const float* Wk   = (const float*)d_in[4];
    const float* bk   = (const float*)d_in[5];
    const float* Wv   = (const float*)d_in[6];
    const float* bv   = (const float*)d_in[7];
    const float* c1w  = (const float*)d_in[8];
    const float* gam  = (const float*)d_in[9];
    const float* bet  = (const float*)d_in[10];
    const float* chw  = (const float*)d_in[11];
    const float* cww  = (const float*)d_in[12];
    float* out = (float*)d_out;

    float* ws = (float*)d_ws;
    float* q  = ws;                        // 3145728 f32
    float* k  = q  + 3145728;
    float* v  = k  + 3145728;
    float* xh = v  + 3145728;              // 49152
    float* xw = xh + 49152;
    float* y  = xw + 49152;                // 24576
    float* sh = y  + 24576;
    float* sw = sh + 49152;
    _Float16* Xh  = (_Float16*)(sw + 49152);   // 3145728 halves
    _Float16* Xl  = Xh + 3145728;
    _Float16* Wth = Xl + 3145728;              // 1769472 halves
    _Float16* Wtl = Wth + 1769472;             // total ws ~55.6 MiB

    hipMemsetAsync(xh, 0, 2 * 49152 * sizeof(float), stream);

    prep_x<<<1536, 256, 0, stream>>>(X, Xh, Xl);
    prep_w<<<864, 256, 0, stream>>>(Wq, Wk, Wv, Wth, Wtl);
    qkv_mfma<<<576, 256, 0, stream>>>(Xh, Xl, Wth, Wtl,
        X, Wq, bq, Wk, bk, Wv, bv, q, k, v);
    score_sums<<<dim3(8, 8, 96), 256, 0, stream>>>(q, k, xh, xw);
    small_ops<<<1, 1024, 0, stream>>>(xh, xw, c1w, gam, bet, chw, cww, y, sh, sw);
    attn_pv<<<dim3(8, 96), 256, 0, stream>>>(q, k, v, mask, sh, sw, out);
}